// Round 1
// 1273.113 us; speedup vs baseline: 1.3945x; 1.3945x over previous
//
#include <hip/hip_runtime.h>

// MCTransformer: x+pe -> QKV proj (relu, q*D^-0.5) -> softmax(qk^T) -> attn@v
//                -> residual + LayerNorm. Outputs: x_out [8192,10,1024] f32, attn [8192,10,10] f32.
//
// v2: GEMM upgraded to the 256x256 8-phase template (T2 XOR-swizzle + T3/T4 counted
//     vmcnt + T5 setprio); attention split into attn_s (K in LDS, 20KB) + pv_ln
//     (V in LDS, 20KB) for 4x the occupancy of the old fused attn_ln.

typedef __attribute__((ext_vector_type(8))) _Float16 h8_t;
typedef __attribute__((ext_vector_type(4))) _Float16 h4_t;
typedef __attribute__((ext_vector_type(2))) _Float16 h2_t;
typedef __attribute__((ext_vector_type(4))) float f32x4_t;

#define B_DIM 8192
#define T_DIM 10
#define D_DIM 1024
#define M_DIM (B_DIM * T_DIM)   // 81920
#define N_DIM (3 * D_DIM)       // 3072
#define K_DIM D_DIM             // 1024

// ---------------- prep: weights fp32 -> fp16, concat q|k|v ----------------
__global__ void prep_w(const float* __restrict__ Wq, const float* __restrict__ Wk,
                       const float* __restrict__ Wv, const float* __restrict__ bq,
                       const float* __restrict__ bk, const float* __restrict__ bv,
                       _Float16* __restrict__ Wc, float* __restrict__ biasc) {
    int idx = blockIdx.x * 256 + threadIdx.x;          // 0 .. 3072*1024-1
    int n = idx >> 10;
    int d = idx & 1023;
    const float* src = (n < 1024) ? Wq : (n < 2048) ? Wk : Wv;
    Wc[idx] = (_Float16)src[(n & 1023) * 1024 + d];
    if (idx < 3072) {
        const float* bsrc = (idx < 1024) ? bq : (idx < 2048) ? bk : bv;
        biasc[idx] = bsrc[idx & 1023];
    }
}

// ---------------- prep: xpe = fp16(x + pe) ----------------
__global__ void prep_x(const float* __restrict__ x, const float* __restrict__ pe,
                       _Float16* __restrict__ xpe) {
    int i4 = blockIdx.x * 256 + threadIdx.x;           // float4 index
    int eidx = i4 * 4;
    int row = eidx >> 10;                              // m = b*10 + t
    int t = row % 10;
    int d = eidx & 1023;
    float4 xv = *(const float4*)(x + eidx);
    float4 pv = *(const float4*)(pe + (t << 10) + d);
    h4_t o = { (_Float16)(xv.x + pv.x), (_Float16)(xv.y + pv.y),
               (_Float16)(xv.z + pv.z), (_Float16)(xv.w + pv.w) };
    *(h4_t*)(xpe + eidx) = o;
}

// ---------------- GEMM: qkv = relu(xpe @ Wc^T + bias), q scaled ----------------
// 256x256 tile, BK=64, 8 waves (2Mx4N), 128KB LDS double-buffered, 8-phase schedule.
__device__ __forceinline__ void load_lds16(const _Float16* g, _Float16* l) {
    // LDS dest is wave-uniform base; HW scatters lane i -> base + i*16B.
    __builtin_amdgcn_global_load_lds((const __attribute__((address_space(1))) void*)g,
                                     (__attribute__((address_space(3))) void*)l,
                                     16, 0, 0);
}

#define BARRIER() __builtin_amdgcn_s_barrier()
#define VMW(n) asm volatile("s_waitcnt vmcnt(" #n ")" ::: "memory")

__global__ __launch_bounds__(512, 2) void gemm_qkv(const _Float16* __restrict__ A,   // [M][K]
                                                   const _Float16* __restrict__ Bt,  // [N][K]
                                                   const float* __restrict__ bias,   // [N]
                                                   _Float16* __restrict__ qkv) {     // [M][N]
    // 4 tiles of 256x64 fp16: [buf0.A][buf0.B][buf1.A][buf1.B] = 128 KiB
    __shared__ _Float16 lds[4][256 * 64];
    const int tid = threadIdx.x;
    const int wave = tid >> 6, lane = tid & 63;
    const int quad = lane >> 4, l16 = lane & 15;
    const int wm = (wave >> 2) * 128, wn = (wave & 3) * 64;

    // XCD-aware bijective swizzle: 3840 wgs, 480 per XCD; n-tile fastest for A reuse.
    int bid = blockIdx.x;
    int wg = (bid & 7) * 480 + (bid >> 3);
    int mt = wg / 12, nt = wg - mt * 12;
    const int m0 = mt * 256, n0 = nt * 256;

    const _Float16* GA = A  + (size_t)m0 * K_DIM;
    const _Float16* GB = Bt + (size_t)n0 * K_DIM;
    // staging: lane covers LDS row r0+(lane>>3), col-byte (lane&7)*16.
    // Source col is pre-swizzled (rule 21): col ^ ((row&7)<<4) so a linear LDS write
    // holds XOR-swizzled data; reads apply the same XOR -> conflict-free ds_read_b128.
    const int srco = (lane >> 3) * K_DIM + ((lane & 7) ^ (lane >> 3)) * 8;
    const int swz = (l16 & 7) << 4;

    _Float16* const LA0 = lds[0]; _Float16* const LB0 = lds[1];
    _Float16* const LA1 = lds[2]; _Float16* const LB1 = lds[3];

    // A half mh: rows {mh*64..+63} u {128+mh*64..+63}; 2 wave-loads per wave.
#define STAGE_A(L, kt, mh) do { \
        int r0_ = (mh) * 64 + wave * 8; \
        load_lds16(GA + (size_t)r0_ * K_DIM + (kt) + srco, (L) + r0_ * 64); \
        load_lds16(GA + (size_t)(r0_ + 128) * K_DIM + (kt) + srco, (L) + (r0_ + 128) * 64); \
    } while (0)
    // B half nh: rows {nh*32..+31} u {64+nh*32..} u {128+nh*32..} u {192+nh*32..}.
#define STAGE_B(L, kt, nh) do { \
        int r0_ = (wave >> 2) * 64 + (nh) * 32 + (wave & 3) * 8; \
        load_lds16(GB + (size_t)r0_ * K_DIM + (kt) + srco, (L) + r0_ * 64); \
        int r1_ = (((wave + 8) >> 2) * 64) + (nh) * 32 + (wave & 3) * 8; \
        load_lds16(GB + (size_t)r1_ * K_DIM + (kt) + srco, (L) + r1_ * 64); \
    } while (0)

#define RD(L, row, ks) (*(const h8_t*)((const char*)(L) + (row) * 128 + (((ks) * 64 + quad * 16) ^ swz)))

    h8_t af[4][2], bf[2][2];
    f32x4_t acc[8][4] = {};

#define PH_COMPUTE(LA_, LB_, mh, nh, rdA, rdB) do { \
        if (rdA) { \
            _Pragma("unroll") for (int m4_ = 0; m4_ < 4; m4_++) { \
                af[m4_][0] = RD(LA_, wm + (mh) * 64 + m4_ * 16 + l16, 0); \
                af[m4_][1] = RD(LA_, wm + (mh) * 64 + m4_ * 16 + l16, 1); } } \
        if (rdB) { \
            _Pragma("unroll") for (int n2_ = 0; n2_ < 2; n2_++) { \
                bf[n2_][0] = RD(LB_, wn + (nh) * 32 + n2_ * 16 + l16, 0); \
                bf[n2_][1] = RD(LB_, wn + (nh) * 32 + n2_ * 16 + l16, 1); } } \
    } while (0)

#define PH_MFMA(mh, nh) do { \
        __builtin_amdgcn_s_setprio(1); \
        _Pragma("unroll") for (int m4_ = 0; m4_ < 4; m4_++) \
        _Pragma("unroll") for (int n2_ = 0; n2_ < 2; n2_++) { \
            acc[(mh) * 4 + m4_][(nh) * 2 + n2_] = __builtin_amdgcn_mfma_f32_16x16x32_f16( \
                af[m4_][0], bf[n2_][0], acc[(mh) * 4 + m4_][(nh) * 2 + n2_], 0, 0, 0); \
            acc[(mh) * 4 + m4_][(nh) * 2 + n2_] = __builtin_amdgcn_mfma_f32_16x16x32_f16( \
                af[m4_][1], bf[n2_][1], acc[(mh) * 4 + m4_][(nh) * 2 + n2_], 0, 0, 0); } \
        __builtin_amdgcn_s_setprio(0); \
    } while (0)

    // prologue: tile0 (buf0, all 4 halves) + tile1 (buf1, A-h0, B-h1); drain to 4.
    STAGE_A(LA0, 0, 0);
    STAGE_B(LB0, 0, 1);
    STAGE_A(LA0, 0, 1);
    STAGE_B(LB0, 0, 0);
    STAGE_A(LA1, 64, 0);
    STAGE_B(LB1, 64, 1);
    VMW(4);
    BARRIER();

    // main loop: 8 iterations x 2 K-tiles. Phase = { ds_read frags; stage 1 half-tile;
    // [vmcnt(4) at ph3/ph7]; barrier; 16 MFMA }. Stage targets released >=2 phases ago
    // (WAR safe); every read's stage is outside the newest-4 window at its gate (RAW safe).
    for (int i = 0; i < 8; i++) {
        const int k1 = ((2 * i + 1) & 15) * 64;
        const int k2 = ((2 * i + 2) & 15) * 64;
        const int k3 = ((2 * i + 3) & 15) * 64;

        PH_COMPUTE(LA0, LB0, 0, 0, 1, 1);  STAGE_A(LA1, k1, 1);  BARRIER();  PH_MFMA(0, 0);
        PH_COMPUTE(LA0, LB0, 0, 1, 0, 1);  STAGE_B(LB1, k1, 0);  BARRIER();  PH_MFMA(0, 1);
        PH_COMPUTE(LA0, LB0, 1, 1, 1, 0);  STAGE_A(LA0, k2, 0);  BARRIER();  PH_MFMA(1, 1);
        PH_COMPUTE(LA0, LB0, 1, 0, 0, 1);  STAGE_B(LB0, k2, 1);  VMW(4);  BARRIER();  PH_MFMA(1, 0);
        PH_COMPUTE(LA1, LB1, 0, 0, 1, 1);  STAGE_A(LA0, k2, 1);  BARRIER();  PH_MFMA(0, 0);
        PH_COMPUTE(LA1, LB1, 0, 1, 0, 1);  STAGE_B(LB0, k2, 0);  BARRIER();  PH_MFMA(0, 1);
        PH_COMPUTE(LA1, LB1, 1, 1, 1, 0);  STAGE_A(LA1, k3, 0);  BARRIER();  PH_MFMA(1, 1);
        PH_COMPUTE(LA1, LB1, 1, 0, 0, 1);  STAGE_B(LB1, k3, 1);  VMW(4);  BARRIER();  PH_MFMA(1, 0);
    }
    VMW(0);

    // epilogue: bias + relu (+ q scale), store fp16. C/D layout: row=quad*4+r, col=l16.
#pragma unroll
    for (int jf = 0; jf < 4; jf++) {
        int ncol = n0 + wn + jf * 16 + l16;
        float bi = bias[ncol];
        float sc = (ncol < 1024) ? 0.03125f : 1.0f;   // D^-0.5 on q only
#pragma unroll
        for (int mf = 0; mf < 8; mf++) {
            int mrow = m0 + wm + mf * 16 + quad * 4;
#pragma unroll
            for (int r = 0; r < 4; r++) {
                float v = fmaxf(acc[mf][jf][r] + bi, 0.0f) * sc;
                qkv[(size_t)(mrow + r) * N_DIM + ncol] = (_Float16)v;
            }
        }
    }
#undef STAGE_A
#undef STAGE_B
#undef RD
#undef PH_COMPUTE
#undef PH_MFMA
}

// ---------------- attn_s: S = q.k^T, softmax -> attn [8192,10,10] ----------------
// Block = 1 batch. Only K staged (20KB LDS -> 8 blocks/CU). Wave per q-row group;
// dot over lane slices [l*8..+7] u [512+l*8..+7] (dense, conflict-free), full-wave
// butterfly reduce, softmax computed redundantly in all lanes (no LDS, no 2nd sync).
__global__ __launch_bounds__(256) void attn_s(const _Float16* __restrict__ qkv,
                                              float* __restrict__ attnout) {
    __shared__ __align__(16) _Float16 sk[10 * 1024];
    const int tid = threadIdx.x;
    const int wave = tid >> 6, lane = tid & 63;
    const int b = blockIdx.x;
    const size_t base = (size_t)b * 10 * N_DIM;
#pragma unroll
    for (int c = 0; c < 5; c++) {
        int ch = c * 256 + tid;                         // 0..1279
        int r = ch >> 7;
        int col = (ch & 127) * 8;
        *(uint4*)(sk + r * 1024 + col) = *(const uint4*)(qkv + base + (size_t)r * N_DIM + 1024 + col);
    }
    __syncthreads();
    const int e0 = lane * 8;
    for (int t = wave; t < 10; t += 4) {
        h8_t q0 = *(const h8_t*)(qkv + base + (size_t)t * N_DIM + e0);
        h8_t q1 = *(const h8_t*)(qkv + base + (size_t)t * N_DIM + 512 + e0);
        float S[10];
#pragma unroll
        for (int s = 0; s < 10; s++) {
            h8_t k0 = *(const h8_t*)(sk + s * 1024 + e0);
            h8_t k1 = *(const h8_t*)(sk + s * 1024 + 512 + e0);
            float sum = 0.0f;
#if __has_builtin(__builtin_amdgcn_fdot2)
#pragma unroll
            for (int j = 0; j < 4; j++) {
                h2_t qa = { q0[2 * j], q0[2 * j + 1] }, ka = { k0[2 * j], k0[2 * j + 1] };
                h2_t qb = { q1[2 * j], q1[2 * j + 1] }, kb = { k1[2 * j], k1[2 * j + 1] };
                sum = __builtin_amdgcn_fdot2(qa, ka, sum, false);
                sum = __builtin_amdgcn_fdot2(qb, kb, sum, false);
            }
#else
#pragma unroll
            for (int j = 0; j < 8; j++)
                sum += (float)q0[j] * (float)k0[j] + (float)q1[j] * (float)k1[j];
#endif
#pragma unroll
            for (int off = 32; off > 0; off >>= 1) sum += __shfl_xor(sum, off);
            S[s] = sum;                                 // all lanes hold S[t][s]
        }
        float mx = -1e30f;
#pragma unroll
        for (int s = 0; s < 10; s++) mx = fmaxf(mx, S[s]);
        float den = 0.0f;
#pragma unroll
        for (int s = 0; s < 10; s++) { S[s] = __expf(S[s] - mx); den += S[s]; }
        float inv = 1.0f / den;
#pragma unroll
        for (int s = 0; s < 10; s++)
            if (lane == s) attnout[(size_t)b * 100 + t * 10 + s] = S[s] * inv;
    }
}

// ---------------- pv_ln: out = P@v, residual (x+pe), LayerNorm ----------------
// Block = 1 batch. Only V staged (20KB LDS -> 8 blocks/CU). f32 accumulation.
__global__ __launch_bounds__(256) void pv_ln(const _Float16* __restrict__ qkv,
                                             const float* __restrict__ P,
                                             const float* __restrict__ x,
                                             const float* __restrict__ pe,
                                             const float* __restrict__ gamma,
                                             const float* __restrict__ beta,
                                             float* __restrict__ xout) {
    __shared__ __align__(16) _Float16 sv[10 * 1024];
    const int tid = threadIdx.x;
    const int wave = tid >> 6, lane = tid & 63;
    const int b = blockIdx.x;
    const size_t base = (size_t)b * 10 * N_DIM;
#pragma unroll
    for (int c = 0; c < 5; c++) {
        int ch = c * 256 + tid;
        int r = ch >> 7;
        int col = (ch & 127) * 8;
        *(uint4*)(sv + r * 1024 + col) = *(const uint4*)(qkv + base + (size_t)r * N_DIM + 2048 + col);
    }
    __syncthreads();
    const int e0 = lane * 8;
    for (int t = wave; t < 10; t += 4) {
        float p[10];
#pragma unroll
        for (int s = 0; s < 10; s++) p[s] = P[(size_t)b * 100 + t * 10 + s];
        float o0[8] = {}, o1[8] = {};
#pragma unroll
        for (int s = 0; s < 10; s++) {
            h8_t v0 = *(const h8_t*)(sv + s * 1024 + e0);
            h8_t v1 = *(const h8_t*)(sv + s * 1024 + 512 + e0);
#pragma unroll
            for (int j = 0; j < 8; j++) { o0[j] += p[s] * (float)v0[j]; o1[j] += p[s] * (float)v1[j]; }
        }
        const float* xr = x + ((size_t)b * 10 + t) * 1024;
        const float* pr = pe + t * 1024;
        float w0[8], w1[8];
        float sum = 0.0f, sq = 0.0f;
#pragma unroll
        for (int j = 0; j < 8; j++) {
            float a = xr[e0 + j] + pr[e0 + j] + o0[j];
            float c2 = xr[512 + e0 + j] + pr[512 + e0 + j] + o1[j];
            w0[j] = a; w1[j] = c2; sum += a + c2; sq += a * a + c2 * c2;
        }
#pragma unroll
        for (int off = 32; off > 0; off >>= 1) { sum += __shfl_xor(sum, off); sq += __shfl_xor(sq, off); }
        float mu = sum * (1.0f / 1024.0f);
        float var = sq * (1.0f / 1024.0f) - mu * mu;
        float rs = rsqrtf(var + 1e-5f);
        float* out = xout + ((size_t)b * 10 + t) * 1024;
#pragma unroll
        for (int j = 0; j < 8; j++) {
            out[e0 + j]       = (w0[j] - mu) * rs * gamma[e0 + j] + beta[e0 + j];
            out[512 + e0 + j] = (w1[j] - mu) * rs * gamma[512 + e0 + j] + beta[512 + e0 + j];
        }
    }
}

// ---------------- launch ----------------
extern "C" void kernel_launch(void* const* d_in, const int* in_sizes, int n_in,
                              void* d_out, int out_size, void* d_ws, size_t ws_size,
                              hipStream_t stream) {
    const float* x     = (const float*)d_in[0];
    const float* pe    = (const float*)d_in[1];
    const float* Wq    = (const float*)d_in[2];
    const float* bq    = (const float*)d_in[3];
    const float* Wk    = (const float*)d_in[4];
    const float* bk    = (const float*)d_in[5];
    const float* Wv    = (const float*)d_in[6];
    const float* bv    = (const float*)d_in[7];
    const float* gamma = (const float*)d_in[8];
    const float* beta  = (const float*)d_in[9];

    float* xout    = (float*)d_out;
    float* attnout = xout + (size_t)M_DIM * D_DIM;   // outputs concatenated: x then attn

    // workspace layout (bytes):
    //   xpe  fp16 [81920][1024] : [0,          167772160)
    //   Wc   fp16 [3072][1024]  : [167772160,  174063616)
    //   bias f32  [3072]        : [174063616,  174075904)
    //   qkv  fp16 [81920][3072] : [174075904,  677392384)
    char* ws = (char*)d_ws;
    _Float16* xpe   = (_Float16*)ws;
    _Float16* Wc    = (_Float16*)(ws + 167772160);
    float*    biasc = (float*)   (ws + 174063616);
    _Float16* qkv   = (_Float16*)(ws + 174075904);

    prep_w<<<dim3((N_DIM * K_DIM) / 256), 256, 0, stream>>>(Wq, Wk, Wv, bq, bk, bv, Wc, biasc);
    prep_x<<<dim3((M_DIM * D_DIM) / 1024), 256, 0, stream>>>(x, pe, xpe);
    gemm_qkv<<<dim3((M_DIM / 256) * (N_DIM / 256)), 512, 0, stream>>>(xpe, Wc, biasc, qkv);
    attn_s<<<dim3(B_DIM), 256, 0, stream>>>(qkv, attnout);
    pv_ln<<<dim3(B_DIM), 256, 0, stream>>>(qkv, attnout, x, pe, gamma, beta, xout);
}